// Round 2
// baseline (121.417 us; speedup 1.0000x reference)
//
#include <hip/hip_runtime.h>

#define K_DIM 4096
#define N_DIM 8192
#define RBLK 32                 // row-blocks for column-sum partials (128 rows each)
#define CBLK 8                  // col-blocks (1024 cols each)

// ws float layout (all plain stores, no pre-zeroing required):
// [0, RBLK*N)                   : partial column sums (reused by both passes)
// [RBLK*N + 0N, +1N)            : prior_eps
// [+1N, +2N)                    : dope
// [+2N, +3N)                    : Tt (tanh(prior_eps/2), valid when Hxs == 0)
// after that: flag (1 int), nzp (256 ints)

__device__ __forceinline__ float fast_tanh_half(float h) {
    // tanh(h/2) = 1 - 2/(e^h + 1)
    float e = __expf(h);
    float r = __builtin_amdgcn_rcpf(e + 1.0f);
    return __builtin_fmaf(-2.0f, r, 1.0f);
}

// out = clip(2*atanh(P/t), -1, 1) for t != 0, else 0.
// 2*atanh(P/t) = ln((t+P)/(t-P))
__device__ __forceinline__ float check_msg(float t, float P) {
    if (t == 0.0f) return 0.0f;
    float num = t + P;
    float den = t - P;
    float q = num * __builtin_amdgcn_rcpf(den);
    float m = 0.69314718055994531f * __log2f(q);
    return fminf(fmaxf(m, -1.0f), 1.0f);
}

// Partial column sums over [K,N] f32. grid=(CBLK, RBLK), block=256.
// Each thread: 4 consecutive cols x (K/RBLK) rows. Plain stores.
__global__ __launch_bounds__(256) void colsum_part_kernel(const float* __restrict__ M,
                                                          float* __restrict__ partial,
                                                          int* __restrict__ nzp) {
    const int c0 = blockIdx.x * 1024 + threadIdx.x * 4;
    const int r0 = blockIdx.y * (K_DIM / RBLK);
    const float4* p = reinterpret_cast<const float4*>(M + (size_t)r0 * N_DIM + c0);
    float sx = 0.f, sy = 0.f, sz = 0.f, sw = 0.f;
    bool nz = false;
    #pragma unroll 4
    for (int r = 0; r < K_DIM / RBLK; ++r) {
        float4 v = p[(size_t)r * (N_DIM / 4)];
        sx += v.x; sy += v.y; sz += v.z; sw += v.w;
        nz = nz || (v.x != 0.f) || (v.y != 0.f) || (v.z != 0.f) || (v.w != 0.f);
    }
    float4 s; s.x = sx; s.y = sy; s.z = sz; s.w = sw;
    reinterpret_cast<float4*>(partial + (size_t)blockIdx.y * N_DIM)[c0 / 4] = s;

    if (nzp != nullptr) {
        __shared__ int snz;
        if (threadIdx.x == 0) snz = 0;
        __syncthreads();
        if (__any(nz ? 1 : 0)) {
            if ((threadIdx.x & 63) == 0) atomicOr(&snz, 1);   // LDS atomic only
        }
        __syncthreads();
        if (threadIdx.x == 0)
            nzp[blockIdx.y * gridDim.x + blockIdx.x] = snz;    // plain global store
    }
}

// Fused reduce + per-column prep. grid = N/256, block = 256.
// Also: block 0 OR-reduces nzp[256] -> flag (plain store).
__global__ __launch_bounds__(256) void prep_kernel(const float* __restrict__ ps,
                                                   const float* __restrict__ Min,
                                                   const float* __restrict__ partial,
                                                   const int* __restrict__ nzp,
                                                   float* __restrict__ prior_eps,
                                                   float* __restrict__ dope_out,
                                                   float* __restrict__ Tt,
                                                   int* __restrict__ flag) {
    const int n = blockIdx.x * 256 + threadIdx.x;
    float cs = 0.0f;
    #pragma unroll
    for (int r = 0; r < RBLK; ++r) cs += partial[(size_t)r * N_DIM + n];

    const float INFCAP = 100.0f;
    const float EPSV = 1e-4f;

    float p0 = ps[2 * n], p1 = ps[2 * n + 1];
    float p1n = p1 / (p0 + p1);
    float dope = logf(1.0f - p1n) - logf(p1n);

    float m0 = Min[2 * n], m1 = Min[2 * n + 1];
    float m1n = m1 / (m0 + m1);
    float phi = logf(1.0f - m1n) - logf(m1n);

    float prior = dope + phi + cs;
    prior = fminf(fmaxf(prior, -INFCAP), INFCAP);
    float pe = prior + EPSV;

    prior_eps[n] = pe;
    dope_out[n] = dope;
    Tt[n] = tanhf(pe * 0.5f);

    if (blockIdx.x == 0) {
        int v = nzp[threadIdx.x];                 // exactly 256 entries
        int any = __any(v ? 1 : 0) ? 1 : 0;
        __shared__ int w[4];
        if ((threadIdx.x & 63) == 0) w[threadIdx.x >> 6] = any;
        __syncthreads();
        if (threadIdx.x == 0) flag[0] = (w[0] | w[1] | w[2] | w[3]);
    }
}

// Main check-node update. grid = K blocks, 256 threads. One block per row.
__global__ __launch_bounds__(256) void row_kernel(const float* __restrict__ Hxs,
                                                  const int* __restrict__ H,
                                                  const int* __restrict__ x,
                                                  const float* __restrict__ prior_eps,
                                                  const float* __restrict__ Tt,
                                                  const int* __restrict__ flag,
                                                  float* __restrict__ out) {
    const int k = blockIdx.x;
    const int tid = threadIdx.x;
    const size_t rowoff = (size_t)k * N_DIM;
    const int4* H4 = reinterpret_cast<const int4*>(H + rowoff);
    const float4* T4 = reinterpret_cast<const float4*>(Tt);
    const float4* HX4 = reinterpret_cast<const float4*>(Hxs + rowoff);
    const float4* PE4 = reinterpret_cast<const float4*>(prior_eps);

    float t[32];
    float lp = 1.0f;

    if (*flag == 0) {
        // Fast path: Hxs is identically zero -> tanh depends only on column.
        #pragma unroll
        for (int i = 0; i < 8; ++i) {
            const int idx = i * 256 + tid;
            const int4 h = H4[idx];
            const float4 tv = T4[idx];
            float t0 = h.x ? tv.x : 0.0f;
            float t1 = h.y ? tv.y : 0.0f;
            float t2 = h.z ? tv.z : 0.0f;
            float t3 = h.w ? tv.w : 0.0f;
            t[i * 4 + 0] = t0; t[i * 4 + 1] = t1;
            t[i * 4 + 2] = t2; t[i * 4 + 3] = t3;
            lp *= (t0 == 0.0f) ? 1.0f : t0;
            lp *= (t1 == 0.0f) ? 1.0f : t1;
            lp *= (t2 == 0.0f) ? 1.0f : t2;
            lp *= (t3 == 0.0f) ? 1.0f : t3;
        }
    } else {
        // General path: Hsx = prior_eps*H - Hxs, t = tanh(Hsx/2)
        #pragma unroll
        for (int i = 0; i < 8; ++i) {
            const int idx = i * 256 + tid;
            const int4 h = H4[idx];
            const float4 hx = HX4[idx];
            const float4 pe = PE4[idx];
            float t0 = fast_tanh_half((h.x ? pe.x : 0.0f) - hx.x);
            float t1 = fast_tanh_half((h.y ? pe.y : 0.0f) - hx.y);
            float t2 = fast_tanh_half((h.z ? pe.z : 0.0f) - hx.z);
            float t3 = fast_tanh_half((h.w ? pe.w : 0.0f) - hx.w);
            t[i * 4 + 0] = t0; t[i * 4 + 1] = t1;
            t[i * 4 + 2] = t2; t[i * 4 + 3] = t3;
            lp *= (t0 == 0.0f) ? 1.0f : t0;
            lp *= (t1 == 0.0f) ? 1.0f : t1;
            lp *= (t2 == 0.0f) ? 1.0f : t2;
            lp *= (t3 == 0.0f) ? 1.0f : t3;
        }
    }

    // Block-wide product: wave butterfly then cross-wave via LDS.
    #pragma unroll
    for (int off = 1; off < 64; off <<= 1)
        lp *= __shfl_xor(lp, off);
    __shared__ float wp[4];
    if ((tid & 63) == 0) wp[tid >> 6] = lp;
    __syncthreads();
    const float prod = wp[0] * wp[1] * wp[2] * wp[3];

    const float sgn = 1.0f - 2.0f * (float)x[k];
    const float P = sgn * prod;

    float4* orow = reinterpret_cast<float4*>(out + rowoff);
    #pragma unroll
    for (int i = 0; i < 8; ++i) {
        const int idx = i * 256 + tid;
        float4 o;
        o.x = check_msg(t[i * 4 + 0], P);
        o.y = check_msg(t[i * 4 + 1], P);
        o.z = check_msg(t[i * 4 + 2], P);
        o.w = check_msg(t[i * 4 + 3], P);
        orow[idx] = o;
    }
}

// Fused reduce + output beliefs. grid = N/256, block = 256.
__global__ __launch_bounds__(256) void final_kernel(const float* __restrict__ partial,
                                                    const float* __restrict__ dope,
                                                    float* __restrict__ Mout) {
    const int n = blockIdx.x * 256 + threadIdx.x;
    float cs = 0.0f;
    #pragma unroll
    for (int r = 0; r < RBLK; ++r) cs += partial[(size_t)r * N_DIM + n];
    float z = (1.0f - tanhf((cs + dope[n]) * 0.5f)) * 0.5f;
    float2 m; m.x = 1.0f - z; m.y = z;
    reinterpret_cast<float2*>(Mout)[n] = m;
}

extern "C" void kernel_launch(void* const* d_in, const int* in_sizes, int n_in,
                              void* d_out, int out_size, void* d_ws, size_t ws_size,
                              hipStream_t stream) {
    (void)in_sizes; (void)n_in; (void)out_size; (void)ws_size;
    const float* ps  = (const float*)d_in[0];
    const float* Min = (const float*)d_in[1];
    const float* Hxs = (const float*)d_in[2];
    const int*   x   = (const int*)d_in[3];
    const int*   H   = (const int*)d_in[4];

    float* out = (float*)d_out;
    float* Mout = out;                       // N*2 floats
    float* Hxs_new = out + 2 * N_DIM;        // K*N floats

    float* ws = (float*)d_ws;
    float* partial    = ws;                                  // RBLK*N floats (1 MB)
    float* prior_eps  = ws + (size_t)RBLK * N_DIM;
    float* dope       = prior_eps + N_DIM;
    float* Tt         = dope + N_DIM;
    int*   flag       = (int*)(Tt + N_DIM);
    int*   nzp        = flag + 64;                           // 256 ints

    dim3 csgrid(CBLK, RBLK);
    colsum_part_kernel<<<csgrid, 256, 0, stream>>>(Hxs, partial, nzp);

    prep_kernel<<<N_DIM / 256, 256, 0, stream>>>(ps, Min, partial, nzp,
                                                 prior_eps, dope, Tt, flag);

    row_kernel<<<K_DIM, 256, 0, stream>>>(Hxs, H, x, prior_eps, Tt, flag, Hxs_new);

    colsum_part_kernel<<<csgrid, 256, 0, stream>>>(Hxs_new, partial, nullptr);

    final_kernel<<<N_DIM / 256, 256, 0, stream>>>(partial, dope, Mout);
}

// Round 3
// 106.871 us; speedup vs baseline: 1.1361x; 1.1361x over previous
//
#include <hip/hip_runtime.h>

#define K_DIM 4096
#define N_DIM 8192
#define RBLK 64                 // row-blocks for column-sum partials (64 rows each)
#define CBLK 8                  // col-blocks (1024 cols each)

// ws float layout (all plain stores, no pre-zeroing required):
// [0, RBLK*N)          : partial column sums (reused by both passes)  (2 MB)
// [RBLK*N, +1N)        : prior_eps
// [+1N, +2N)           : dope
// [+2N, +3N)           : Tt (tanh(prior_eps/2), valid when Hxs == 0)
// after that: flag (1 int), nzp (512 ints)

__device__ __forceinline__ float fast_tanh_half(float h) {
    // tanh(h/2) = 1 - 2/(e^h + 1)
    float e = __expf(h);
    float r = __builtin_amdgcn_rcpf(e + 1.0f);
    return __builtin_fmaf(-2.0f, r, 1.0f);
}

// out = clip(2*atanh(P/t), -1, 1) for t != 0, else 0.
// 2*atanh(P/t) = ln((t+P)/(t-P))
__device__ __forceinline__ float check_msg(float t, float P) {
    float num = t + P;
    float den = t - P;
    float q = num * __builtin_amdgcn_rcpf(den);
    float m = 0.69314718055994531f * __log2f(q);
    m = fminf(fmaxf(m, -1.0f), 1.0f);
    return (t == 0.0f) ? 0.0f : m;
}

// Partial column sums over [K,N] f32. grid=(CBLK, RBLK), block=256.
// Each thread: 4 consecutive cols x (K/RBLK) rows. Plain stores.
__global__ __launch_bounds__(256) void colsum_part_kernel(const float* __restrict__ M,
                                                          float* __restrict__ partial,
                                                          int* __restrict__ nzp) {
    const int c0 = blockIdx.x * 1024 + threadIdx.x * 4;
    const int r0 = blockIdx.y * (K_DIM / RBLK);
    const float4* p = reinterpret_cast<const float4*>(M + (size_t)r0 * N_DIM + c0);
    float sx = 0.f, sy = 0.f, sz = 0.f, sw = 0.f;
    unsigned int nzbits = 0u;
    #pragma unroll 8
    for (int r = 0; r < K_DIM / RBLK; ++r) {
        float4 v = p[(size_t)r * (N_DIM / 4)];
        sx += v.x; sy += v.y; sz += v.z; sw += v.w;
        uint4 u = *reinterpret_cast<const uint4*>(&v);
        nzbits |= (u.x | u.y | u.z | u.w);   // false-positive on -0.0 only -> safe general path
    }
    float4 s; s.x = sx; s.y = sy; s.z = sz; s.w = sw;
    reinterpret_cast<float4*>(partial + (size_t)blockIdx.y * N_DIM)[c0 / 4] = s;

    if (nzp != nullptr) {
        __shared__ int snz;
        if (threadIdx.x == 0) snz = 0;
        __syncthreads();
        if (__any(nzbits != 0u ? 1 : 0)) {
            if ((threadIdx.x & 63) == 0) atomicOr(&snz, 1);   // LDS atomic only
        }
        __syncthreads();
        if (threadIdx.x == 0)
            nzp[blockIdx.y * gridDim.x + blockIdx.x] = snz;    // plain global store
    }
}

// Fused reduce + per-column prep. grid = N/256, block = 256.
// Also: block 0 OR-reduces nzp[512] -> flag (plain store).
__global__ __launch_bounds__(256) void prep_kernel(const float* __restrict__ ps,
                                                   const float* __restrict__ Min,
                                                   const float* __restrict__ partial,
                                                   const int* __restrict__ nzp,
                                                   float* __restrict__ prior_eps,
                                                   float* __restrict__ dope_out,
                                                   float* __restrict__ Tt,
                                                   int* __restrict__ flag) {
    const int n = blockIdx.x * 256 + threadIdx.x;
    float cs = 0.0f;
    #pragma unroll 8
    for (int r = 0; r < RBLK; ++r) cs += partial[(size_t)r * N_DIM + n];

    const float INFCAP = 100.0f;
    const float EPSV = 1e-4f;

    float p0 = ps[2 * n], p1 = ps[2 * n + 1];
    float p1n = p1 / (p0 + p1);
    float dope = logf(1.0f - p1n) - logf(p1n);

    float m0 = Min[2 * n], m1 = Min[2 * n + 1];
    float m1n = m1 / (m0 + m1);
    float phi = logf(1.0f - m1n) - logf(m1n);

    float prior = dope + phi + cs;
    prior = fminf(fmaxf(prior, -INFCAP), INFCAP);
    float pe = prior + EPSV;

    prior_eps[n] = pe;
    dope_out[n] = dope;
    Tt[n] = tanhf(pe * 0.5f);

    if (blockIdx.x == 0) {
        int v = nzp[threadIdx.x] | nzp[threadIdx.x + 256];   // 512 entries
        int any = __any(v ? 1 : 0) ? 1 : 0;
        __shared__ int w[4];
        if ((threadIdx.x & 63) == 0) w[threadIdx.x >> 6] = any;
        __syncthreads();
        if (threadIdx.x == 0) flag[0] = (w[0] | w[1] | w[2] | w[3]);
    }
}

// Main check-node update. grid = K blocks, 256 threads. One block per row.
__global__ __launch_bounds__(256) void row_kernel(const float* __restrict__ Hxs,
                                                  const int* __restrict__ H,
                                                  const int* __restrict__ x,
                                                  const float* __restrict__ prior_eps,
                                                  const float* __restrict__ Tt,
                                                  const int* __restrict__ flag,
                                                  float* __restrict__ out) {
    const int k = blockIdx.x;
    const int tid = threadIdx.x;
    const size_t rowoff = (size_t)k * N_DIM;
    const int4* H4 = reinterpret_cast<const int4*>(H + rowoff);
    const float4* T4 = reinterpret_cast<const float4*>(Tt);
    const float4* HX4 = reinterpret_cast<const float4*>(Hxs + rowoff);
    const float4* PE4 = reinterpret_cast<const float4*>(prior_eps);

    float t[32];
    float lp = 1.0f;

    if (*flag == 0) {
        // Fast path: Hxs is identically zero -> tanh depends only on column.
        // Explicit load phase: all 16 VMEM ops in flight before compute.
        int4 h[8];
        float4 tv[8];
        #pragma unroll
        for (int i = 0; i < 8; ++i) h[i] = H4[i * 256 + tid];
        #pragma unroll
        for (int i = 0; i < 8; ++i) tv[i] = T4[i * 256 + tid];
        #pragma unroll
        for (int i = 0; i < 8; ++i) {
            float t0 = h[i].x ? tv[i].x : 0.0f;
            float t1 = h[i].y ? tv[i].y : 0.0f;
            float t2 = h[i].z ? tv[i].z : 0.0f;
            float t3 = h[i].w ? tv[i].w : 0.0f;
            t[i * 4 + 0] = t0; t[i * 4 + 1] = t1;
            t[i * 4 + 2] = t2; t[i * 4 + 3] = t3;
            lp *= (t0 == 0.0f) ? 1.0f : t0;
            lp *= (t1 == 0.0f) ? 1.0f : t1;
            lp *= (t2 == 0.0f) ? 1.0f : t2;
            lp *= (t3 == 0.0f) ? 1.0f : t3;
        }
    } else {
        // General path: Hsx = prior_eps*H - Hxs, t = tanh(Hsx/2)
        #pragma unroll
        for (int i = 0; i < 8; ++i) {
            const int idx = i * 256 + tid;
            const int4 h = H4[idx];
            const float4 hx = HX4[idx];
            const float4 pe = PE4[idx];
            float t0 = fast_tanh_half((h.x ? pe.x : 0.0f) - hx.x);
            float t1 = fast_tanh_half((h.y ? pe.y : 0.0f) - hx.y);
            float t2 = fast_tanh_half((h.z ? pe.z : 0.0f) - hx.z);
            float t3 = fast_tanh_half((h.w ? pe.w : 0.0f) - hx.w);
            t[i * 4 + 0] = t0; t[i * 4 + 1] = t1;
            t[i * 4 + 2] = t2; t[i * 4 + 3] = t3;
            lp *= (t0 == 0.0f) ? 1.0f : t0;
            lp *= (t1 == 0.0f) ? 1.0f : t1;
            lp *= (t2 == 0.0f) ? 1.0f : t2;
            lp *= (t3 == 0.0f) ? 1.0f : t3;
        }
    }

    // Block-wide product: wave butterfly then cross-wave via LDS.
    #pragma unroll
    for (int off = 1; off < 64; off <<= 1)
        lp *= __shfl_xor(lp, off);
    __shared__ float wp[4];
    if ((tid & 63) == 0) wp[tid >> 6] = lp;
    __syncthreads();
    const float prod = wp[0] * wp[1] * wp[2] * wp[3];

    const float sgn = 1.0f - 2.0f * (float)x[k];
    const float P = sgn * prod;

    float4* orow = reinterpret_cast<float4*>(out + rowoff);
    #pragma unroll
    for (int i = 0; i < 8; ++i) {
        const int idx = i * 256 + tid;
        float4 o;
        o.x = check_msg(t[i * 4 + 0], P);
        o.y = check_msg(t[i * 4 + 1], P);
        o.z = check_msg(t[i * 4 + 2], P);
        o.w = check_msg(t[i * 4 + 3], P);
        orow[idx] = o;
    }
}

// Fused reduce + output beliefs. grid = N/256, block = 256.
__global__ __launch_bounds__(256) void final_kernel(const float* __restrict__ partial,
                                                    const float* __restrict__ dope,
                                                    float* __restrict__ Mout) {
    const int n = blockIdx.x * 256 + threadIdx.x;
    float cs = 0.0f;
    #pragma unroll 8
    for (int r = 0; r < RBLK; ++r) cs += partial[(size_t)r * N_DIM + n];
    float z = (1.0f - tanhf((cs + dope[n]) * 0.5f)) * 0.5f;
    float2 m; m.x = 1.0f - z; m.y = z;
    reinterpret_cast<float2*>(Mout)[n] = m;
}

extern "C" void kernel_launch(void* const* d_in, const int* in_sizes, int n_in,
                              void* d_out, int out_size, void* d_ws, size_t ws_size,
                              hipStream_t stream) {
    (void)in_sizes; (void)n_in; (void)out_size; (void)ws_size;
    const float* ps  = (const float*)d_in[0];
    const float* Min = (const float*)d_in[1];
    const float* Hxs = (const float*)d_in[2];
    const int*   x   = (const int*)d_in[3];
    const int*   H   = (const int*)d_in[4];

    float* out = (float*)d_out;
    float* Mout = out;                       // N*2 floats
    float* Hxs_new = out + 2 * N_DIM;        // K*N floats

    float* ws = (float*)d_ws;
    float* partial    = ws;                                  // RBLK*N floats (2 MB)
    float* prior_eps  = ws + (size_t)RBLK * N_DIM;
    float* dope       = prior_eps + N_DIM;
    float* Tt         = dope + N_DIM;
    int*   flag       = (int*)(Tt + N_DIM);
    int*   nzp        = flag + 64;                           // 512 ints

    dim3 csgrid(CBLK, RBLK);
    colsum_part_kernel<<<csgrid, 256, 0, stream>>>(Hxs, partial, nzp);

    prep_kernel<<<N_DIM / 256, 256, 0, stream>>>(ps, Min, partial, nzp,
                                                 prior_eps, dope, Tt, flag);

    row_kernel<<<K_DIM, 256, 0, stream>>>(Hxs, H, x, prior_eps, Tt, flag, Hxs_new);

    colsum_part_kernel<<<csgrid, 256, 0, stream>>>(Hxs_new, partial, nullptr);

    final_kernel<<<N_DIM / 256, 256, 0, stream>>>(partial, dope, Mout);
}